// Round 6
// baseline (346.703 us; speedup 1.0000x reference)
//
#include <hip/hip_runtime.h>
#include <math.h>

#define G  64
#define NG 2048
#define K  16
#define D  256
#define KD (K*D)               // 4096 floats per graph
#define PROWS 128              // rows per block (project/back)
#define NCHUNK (NG/PROWS)      // 16 chunks per graph
#define WPF ((size_t)G * NCHUNK * KD)   // chunk-partial floats (4.2M = 16MB)

typedef float v4f __attribute__((ext_vector_type(4)));

// ---------------------------------------------------------------------------
// Stage 1: WP[g,c][k][d] = sum_{n in 128-row chunk} V[n][k] * x[n][d]
// grid = G*16 x 256T. k-SPLIT: wave kq owns k-quad kq (acc=16 VGPR, no
// cross-wave reduce, 1 barrier). Each wave walks all 128 rows, start offset
// kq*32 (staggered so one wave misses, three hit L1/L2). unroll 8 -> 8
// independent float4 loads in flight/thread; ~24 waves/CU.
// ---------------------------------------------------------------------------
__global__ __launch_bounds__(256, 6) void k_project(const float* __restrict__ x,
                                                    const float* __restrict__ eig,
                                                    float* __restrict__ WP) {
    __shared__ float sV[PROWS * K];      // 8 KB
    const int b  = blockIdx.x;
    const int g  = b >> 4, c = b & 15;
    const int n0 = g * NG + c * PROWS;
    const int t  = threadIdx.x;
    const int d4 = t & 63;
    const int kq = t >> 6;               // wave id = k-quad

    {   // stage 128 rows x 16 k = 512 float4, coalesced
        const float4* e4 = (const float4*)(eig + (size_t)n0 * K);
        float4* s4 = (float4*)sV;
        s4[t]       = e4[t];
        s4[t + 256] = e4[t + 256];
    }
    __syncthreads();

    float acc[4][4];
#pragma unroll
    for (int j = 0; j < 4; ++j)
#pragma unroll
        for (int i = 0; i < 4; ++i) acc[j][i] = 0.f;

    const float4* x4 = (const float4*)x + (size_t)n0 * 64;
    const int rot = kq * 32;
#pragma unroll 8
    for (int i = 0; i < PROWS; ++i) {
        const int n = (i + rot) & (PROWS - 1);
        const float4 xv = x4[n * 64 + d4];
        const float4 v  = *(const float4*)&sV[n * K + kq * 4];   // bcast
        acc[0][0] += v.x * xv.x; acc[0][1] += v.x * xv.y;
        acc[0][2] += v.x * xv.z; acc[0][3] += v.x * xv.w;
        acc[1][0] += v.y * xv.x; acc[1][1] += v.y * xv.y;
        acc[1][2] += v.y * xv.z; acc[1][3] += v.y * xv.w;
        acc[2][0] += v.z * xv.x; acc[2][1] += v.z * xv.y;
        acc[2][2] += v.z * xv.z; acc[2][3] += v.z * xv.w;
        acc[3][0] += v.w * xv.x; acc[3][1] += v.w * xv.y;
        acc[3][2] += v.w * xv.z; acc[3][3] += v.w * xv.w;
    }

    float4* wp4 = (float4*)WP + (size_t)b * (KD / 4);
#pragma unroll
    for (int j = 0; j < 4; ++j)
        wp4[(kq * 4 + j) * 64 + d4] =
            make_float4(acc[j][0], acc[j][1], acc[j][2], acc[j][3]);
}

// ---------------------------------------------------------------------------
// Stage 1b: Xr/Xi[g][k][d] = (sum_c WP[g,c][k][d]) * filt[g][k][d] * {sr,si}[d]
// grid = G*4 x 256T; thread owns one float4; 16 strided loads fully unrolled.
// ---------------------------------------------------------------------------
__global__ __launch_bounds__(256) void k_reduce(const float* __restrict__ WP,
                                                const float* __restrict__ filt,
                                                const float* __restrict__ sr,
                                                const float* __restrict__ si,
                                                float* __restrict__ Xr,
                                                float* __restrict__ Xi) {
    const int b = blockIdx.x;
    const int g = b >> 2, q = b & 3;
    const int f = q * 256 + threadIdx.x;          // float4 index in [0,1024)
    const float4* wp4 = (const float4*)WP + (size_t)g * NCHUNK * (KD / 4);
    float ax = 0.f, ay = 0.f, az = 0.f, aw = 0.f;
#pragma unroll
    for (int w = 0; w < NCHUNK; ++w) {
        const float4 p = wp4[(size_t)w * (KD / 4) + f];
        ax += p.x; ay += p.y; az += p.z; aw += p.w;
    }
    const float4 fl = ((const float4*)filt)[(size_t)g * (KD / 4) + f];
    const int d4 = f & 63;
    const float4 s0 = ((const float4*)sr)[d4];
    const float4 s1 = ((const float4*)si)[d4];
    float4 xr, xi;
    xr.x = ax * fl.x * s0.x; xr.y = ay * fl.y * s0.y;
    xr.z = az * fl.z * s0.z; xr.w = aw * fl.w * s0.w;
    xi.x = ax * fl.x * s1.x; xi.y = ay * fl.y * s1.y;
    xi.z = az * fl.z * s1.z; xi.w = aw * fl.w * s1.w;
    ((float4*)Xr)[(size_t)g * (KD / 4) + f] = xr;
    ((float4*)Xi)[(size_t)g * (KD / 4) + f] = xi;
}

// ---------------------------------------------------------------------------
// Stage 2 (x2): h[g,k,e] = sum_d X[g,k,d] * W[e,d]; norm-gated SiLU over k.
// grid = G*8 (32 e-rows/block), 256T: el=t&31, kg=t>>5 (2 k's each).
// BOTH W (swizzled, per-lane) and X (broadcast) live in LDS -- no scalar
// s_loads in the dot loop (SMEM drains were serializing it).
// ---------------------------------------------------------------------------
template <int LAYER>
__global__ __launch_bounds__(256) void k_mlp(const float* __restrict__ Ar,
                                             const float* __restrict__ Ai,
                                             const float* __restrict__ W,
                                             const float* __restrict__ fs,
                                             float* __restrict__ o0,
                                             float* __restrict__ o1) {
    __shared__ float4 sW[32 * 64];        // 32 KB
    __shared__ float4 sXr[K * 64];        // 16 KB
    __shared__ float4 sXi[K * 64];        // 16 KB
    __shared__ float  sNrm[8 * 32];
    __shared__ float  sSg[32];
    const int b     = blockIdx.x;
    const int g     = b >> 3;
    const int slice = b & 7;
    const int t     = threadIdx.x;

    {   // stage W rows [slice*32, +32), coalesced, XOR-swizzled
        const float4* Wg = (const float4*)W + (size_t)slice * 32 * 64;
#pragma unroll
        for (int it = 0; it < 8; ++it) {
            const int idx = it * 256 + t;        // 0..2047
            const int e = idx >> 6, ds = idx & 63;
            sW[e * 64 + (ds ^ (e & 7))] = Wg[idx];
        }
        // stage X (whole graph slice: 1024 float4 each)
        const float4* ar4 = (const float4*)Ar + (size_t)g * (KD / 4);
        const float4* ai4 = (const float4*)Ai + (size_t)g * (KD / 4);
#pragma unroll
        for (int it = 0; it < 4; ++it) {
            sXr[it * 256 + t] = ar4[it * 256 + t];
            sXi[it * 256 + t] = ai4[it * 256 + t];
        }
    }
    __syncthreads();

    const int el = t & 31;
    const int kg = t >> 5;                 // 0..7, owns k = 2kg, 2kg+1
    const int e  = slice * 32 + el;

    float pr0 = 0.f, pr1 = 0.f, pi0 = 0.f, pi1 = 0.f;
#pragma unroll 8
    for (int ds = 0; ds < 64; ++ds) {
        const float4 w  = sW[el * 64 + (ds ^ (el & 7))];
        const float4 a0 = sXr[(kg * 2) * 64 + ds];       // bcast (half-wave)
        const float4 a1 = sXr[(kg * 2 + 1) * 64 + ds];
        const float4 c0 = sXi[(kg * 2) * 64 + ds];
        const float4 c1 = sXi[(kg * 2 + 1) * 64 + ds];
        pr0 += w.x * a0.x + w.y * a0.y + w.z * a0.z + w.w * a0.w;
        pr1 += w.x * a1.x + w.y * a1.y + w.z * a1.z + w.w * a1.w;
        pi0 += w.x * c0.x + w.y * c0.y + w.z * c0.z + w.w * c0.w;
        pi1 += w.x * c1.x + w.y * c1.y + w.z * c1.z + w.w * c1.w;
    }

    sNrm[kg * 32 + el] = pr0 * pr0 + pi0 * pi0 + pr1 * pr1 + pi1 * pi1;
    __syncthreads();
    if (t < 32) {
        float nrm = 0.f;
#pragma unroll
        for (int w = 0; w < 8; ++w) nrm += sNrm[w * 32 + t];
        sSg[t] = 1.f / (1.f + expf(-sqrtf(nrm)));
    }
    __syncthreads();
    const float sg = sSg[el];

    float* base0 = o0 + (size_t)g * KD + (kg * 2) * D + e;
    if (LAYER == 1) {
        float* base1 = o1 + (size_t)g * KD + (kg * 2) * D + e;
        base0[0] = pr0 * sg; base0[D] = pr1 * sg;
        base1[0] = pi0 * sg; base1[D] = pi1 * sg;
    } else {
        const float f0 = fs[e * 2], f1 = fs[e * 2 + 1];
        base0[0] = (pr0 * f0 + pi0 * f1) * sg;
        base0[D] = (pr1 * f0 + pi1 * f1) * sg;
    }
}

// ---------------------------------------------------------------------------
// Stage 3: out[n,d] = x[n,d] + sum_k V[n,k] * z[g,k,d]
// grid = G*16 x 256T; wave nq owns rows nq*32..; z slice in 16 float4 regs;
// V via LDS broadcast; unroll 8 -> deep ILP; NT stores (bypass L3 so x stays
// resident from k_project's pass).
// ---------------------------------------------------------------------------
__global__ __launch_bounds__(256, 4) void k_back(const float* __restrict__ x,
                                                 const float* __restrict__ eig,
                                                 const float* __restrict__ z,
                                                 float* __restrict__ out) {
    __shared__ float sV[PROWS * K];      // 8 KB
    const int b  = blockIdx.x;
    const int g  = b >> 4, c = b & 15;
    const int n0 = g * NG + c * PROWS;
    const int t  = threadIdx.x;
    const int d4 = t & 63;
    const int nq = t >> 6;
    {
        const float4* e4 = (const float4*)(eig + (size_t)n0 * K);
        float4* s4 = (float4*)sV;
        s4[t]       = e4[t];
        s4[t + 256] = e4[t + 256];
    }
    float4 zr[K];
    const float4* z4 = (const float4*)z + (size_t)g * (KD / 4);
#pragma unroll
    for (int k = 0; k < K; ++k) zr[k] = z4[k * 64 + d4];
    __syncthreads();

    const float4* x4 = (const float4*)x + ((size_t)n0 + nq * 32) * 64;
    v4f* o4 = (v4f*)out + ((size_t)n0 + nq * 32) * 64;
    const float* vbase = sV + nq * 32 * K;
#pragma unroll 8
    for (int n = 0; n < 32; ++n) {
        float4 o = x4[n * 64 + d4];
#pragma unroll
        for (int kq = 0; kq < 4; ++kq) {
            const float4 v = *(const float4*)&vbase[n * K + kq * 4];  // bcast
            o.x += v.x * zr[kq*4+0].x + v.y * zr[kq*4+1].x + v.z * zr[kq*4+2].x + v.w * zr[kq*4+3].x;
            o.y += v.x * zr[kq*4+0].y + v.y * zr[kq*4+1].y + v.z * zr[kq*4+2].y + v.w * zr[kq*4+3].y;
            o.z += v.x * zr[kq*4+0].z + v.y * zr[kq*4+1].z + v.z * zr[kq*4+2].z + v.w * zr[kq*4+3].z;
            o.w += v.x * zr[kq*4+0].w + v.y * zr[kq*4+1].w + v.z * zr[kq*4+2].w + v.w * zr[kq*4+3].w;
        }
        v4f ov; ov.x = o.x; ov.y = o.y; ov.z = o.z; ov.w = o.w;
        __builtin_nontemporal_store(ov, &o4[n * 64 + d4]);
    }
}

// ---------------------------------------------------------------------------
extern "C" void kernel_launch(void* const* d_in, const int* in_sizes, int n_in,
                              void* d_out, int out_size, void* d_ws, size_t ws_size,
                              hipStream_t stream) {
    const float* x    = (const float*)d_in[0];
    const float* eig  = (const float*)d_in[1];
    const float* sr   = (const float*)d_in[2];
    const float* si   = (const float*)d_in[3];
    const float* filt = (const float*)d_in[4];
    const float* W1   = (const float*)d_in[5];
    const float* W2   = (const float*)d_in[6];
    const float* fs   = (const float*)d_in[7];
    float* out = (float*)d_out;

    // Scratch carved from d_out (134MB; fully overwritten by k_back last):
    //   WP: 1024 x KD = 16MB of chunk partials, then Xr/Xi/y1r/y1i (1MB each).
    float* WP  = out;
    float* Xr  = out + WPF;
    float* Xi  = Xr + (size_t)G * KD;
    float* y1r = Xi + (size_t)G * KD;
    float* y1i = y1r + (size_t)G * KD;
    // z is read by k_back while it writes d_out -> lives in ws.
    float* z   = (float*)d_ws;

    k_project<<<G * NCHUNK, 256, 0, stream>>>(x, eig, WP);
    k_reduce<<<G * 4, 256, 0, stream>>>(WP, filt, sr, si, Xr, Xi);
    k_mlp<1><<<G * 8, 256, 0, stream>>>(Xr, Xi, W1, nullptr, y1r, y1i);
    k_mlp<2><<<G * 8, 256, 0, stream>>>(y1r, y1i, W2, fs, z, nullptr);
    k_back<<<G * NCHUNK, 256, 0, stream>>>(x, eig, z, out);
}

// Round 7
// 301.690 us; speedup vs baseline: 1.1492x; 1.1492x over previous
//
#include <hip/hip_runtime.h>
#include <math.h>

#define G  64
#define NG 2048
#define K  16
#define D  256
#define KD (K*D)               // 4096 floats per graph
#define PROWS 256              // rows per block (project): 4 waves x 64 rows
#define NCHUNK (NG/PROWS)      // 8 chunks per graph
#define BROWS 128              // rows per block (back): 4 waves x 32 rows
#define BCHUNK (NG/BROWS)      // 16
#define WPF ((size_t)G * NCHUNK * KD)   // chunk-partial floats (2.1M = 8.4MB)

typedef float v4f __attribute__((ext_vector_type(4)));

// ---------------------------------------------------------------------------
// Stage 1: WP[g,c][k][d] = sum_{n in 256-row chunk} V[n][k] * x[n][d]
// grid = G*8 x 256T (4 waves). DISJOINT row ownership: wave nq owns rows
// [nq*64, nq*64+64) -> every x line fetched exactly once (r6 lesson: any
// wave-overlap in row traversal multiplies HBM fetch). acc[16][4]/thread,
// cross-wave tree reduce in LDS, one 16KB partial per block.
// ---------------------------------------------------------------------------
__global__ __launch_bounds__(256) void k_project(const float* __restrict__ x,
                                                 const float* __restrict__ eig,
                                                 float* __restrict__ WP) {
    __shared__ float sV[PROWS * K];      // 16 KB
    __shared__ float red[2 * KD];        // 32 KB
    const int b  = blockIdx.x;
    const int g  = b >> 3, c = b & 7;
    const int n0 = g * NG + c * PROWS;
    const int t  = threadIdx.x;
    const int d4 = t & 63;
    const int nq = t >> 6;

    {   // stage 256 rows x 16 k = 1024 float4, coalesced
        const float4* e4 = (const float4*)(eig + (size_t)n0 * K);
        float4* s4 = (float4*)sV;
#pragma unroll
        for (int i = 0; i < 4; ++i) s4[i * 256 + t] = e4[i * 256 + t];
    }
    __syncthreads();

    float acc[K][4];
#pragma unroll
    for (int k = 0; k < K; ++k)
#pragma unroll
        for (int j = 0; j < 4; ++j) acc[k][j] = 0.f;

    const float4* x4 = (const float4*)x + ((size_t)n0 + nq * 64) * 64;
    const float* vbase = sV + nq * 64 * K;
#pragma unroll 8
    for (int n = 0; n < 64; ++n) {
        const float4 xv = x4[n * 64 + d4];
#pragma unroll
        for (int kq = 0; kq < 4; ++kq) {
            const float4 v = *(const float4*)&vbase[n * K + kq * 4];  // bcast
            acc[kq*4+0][0] += v.x * xv.x; acc[kq*4+0][1] += v.x * xv.y;
            acc[kq*4+0][2] += v.x * xv.z; acc[kq*4+0][3] += v.x * xv.w;
            acc[kq*4+1][0] += v.y * xv.x; acc[kq*4+1][1] += v.y * xv.y;
            acc[kq*4+1][2] += v.y * xv.z; acc[kq*4+1][3] += v.y * xv.w;
            acc[kq*4+2][0] += v.z * xv.x; acc[kq*4+2][1] += v.z * xv.y;
            acc[kq*4+2][2] += v.z * xv.z; acc[kq*4+2][3] += v.z * xv.w;
            acc[kq*4+3][0] += v.w * xv.x; acc[kq*4+3][1] += v.w * xv.y;
            acc[kq*4+3][2] += v.w * xv.z; acc[kq*4+3][3] += v.w * xv.w;
        }
    }

    // tree reduce: (2,3) -> (0,1) -> 0
    if (nq >= 2) {
#pragma unroll
        for (int k = 0; k < K; ++k)
            *(float4*)&red[(nq - 2) * KD + k * D + d4 * 4] =
                make_float4(acc[k][0], acc[k][1], acc[k][2], acc[k][3]);
    }
    __syncthreads();
    if (nq < 2) {
#pragma unroll
        for (int k = 0; k < K; ++k) {
            const float4 r = *(const float4*)&red[nq * KD + k * D + d4 * 4];
            acc[k][0] += r.x; acc[k][1] += r.y; acc[k][2] += r.z; acc[k][3] += r.w;
        }
    }
    __syncthreads();
    if (nq == 1) {
#pragma unroll
        for (int k = 0; k < K; ++k)
            *(float4*)&red[k * D + d4 * 4] =
                make_float4(acc[k][0], acc[k][1], acc[k][2], acc[k][3]);
    }
    __syncthreads();
    if (nq == 0) {
        float4* wp4 = (float4*)WP + (size_t)b * (KD / 4);
#pragma unroll
        for (int k = 0; k < K; ++k) {
            const float4 r = *(const float4*)&red[k * D + d4 * 4];
            wp4[k * 64 + d4] = make_float4(acc[k][0] + r.x, acc[k][1] + r.y,
                                           acc[k][2] + r.z, acc[k][3] + r.w);
        }
    }
}

// ---------------------------------------------------------------------------
// Stage 1b: Xr/Xi[g][k][d] = (sum_c WP[g,c][k][d]) * filt[g][k][d] * {sr,si}[d]
// grid = G*4 x 256T; thread owns one float4; 8 strided loads fully unrolled.
// ---------------------------------------------------------------------------
__global__ __launch_bounds__(256) void k_reduce(const float* __restrict__ WP,
                                                const float* __restrict__ filt,
                                                const float* __restrict__ sr,
                                                const float* __restrict__ si,
                                                float* __restrict__ Xr,
                                                float* __restrict__ Xi) {
    const int b = blockIdx.x;
    const int g = b >> 2, q = b & 3;
    const int f = q * 256 + threadIdx.x;          // float4 index in [0,1024)
    const float4* wp4 = (const float4*)WP + (size_t)g * NCHUNK * (KD / 4);
    float ax = 0.f, ay = 0.f, az = 0.f, aw = 0.f;
#pragma unroll
    for (int w = 0; w < NCHUNK; ++w) {
        const float4 p = wp4[(size_t)w * (KD / 4) + f];
        ax += p.x; ay += p.y; az += p.z; aw += p.w;
    }
    const float4 fl = ((const float4*)filt)[(size_t)g * (KD / 4) + f];
    const int d4 = f & 63;
    const float4 s0 = ((const float4*)sr)[d4];
    const float4 s1 = ((const float4*)si)[d4];
    float4 xr, xi;
    xr.x = ax * fl.x * s0.x; xr.y = ay * fl.y * s0.y;
    xr.z = az * fl.z * s0.z; xr.w = aw * fl.w * s0.w;
    xi.x = ax * fl.x * s1.x; xi.y = ay * fl.y * s1.y;
    xi.z = az * fl.z * s1.z; xi.w = aw * fl.w * s1.w;
    ((float4*)Xr)[(size_t)g * (KD / 4) + f] = xr;
    ((float4*)Xi)[(size_t)g * (KD / 4) + f] = xi;
}

// ---------------------------------------------------------------------------
// Stage 2 (x2): h[g,k,e] = sum_d X[g,k,d] * W[e,d]; norm-gated SiLU over k.
// grid = G*8 (32 e-rows/block), 256T: el=t&31, kg=t>>5 (2 k's each).
// W (swizzled, per-lane) and X (broadcast) both in LDS.
// ---------------------------------------------------------------------------
template <int LAYER>
__global__ __launch_bounds__(256) void k_mlp(const float* __restrict__ Ar,
                                             const float* __restrict__ Ai,
                                             const float* __restrict__ W,
                                             const float* __restrict__ fs,
                                             float* __restrict__ o0,
                                             float* __restrict__ o1) {
    __shared__ float4 sW[32 * 64];        // 32 KB
    __shared__ float4 sXr[K * 64];        // 16 KB
    __shared__ float4 sXi[K * 64];        // 16 KB
    __shared__ float  sNrm[8 * 32];
    __shared__ float  sSg[32];
    const int b     = blockIdx.x;
    const int g     = b >> 3;
    const int slice = b & 7;
    const int t     = threadIdx.x;

    {   // stage W rows [slice*32, +32), coalesced, XOR-swizzled
        const float4* Wg = (const float4*)W + (size_t)slice * 32 * 64;
#pragma unroll
        for (int it = 0; it < 8; ++it) {
            const int idx = it * 256 + t;        // 0..2047
            const int e = idx >> 6, ds = idx & 63;
            sW[e * 64 + (ds ^ (e & 7))] = Wg[idx];
        }
        const float4* ar4 = (const float4*)Ar + (size_t)g * (KD / 4);
        const float4* ai4 = (const float4*)Ai + (size_t)g * (KD / 4);
#pragma unroll
        for (int it = 0; it < 4; ++it) {
            sXr[it * 256 + t] = ar4[it * 256 + t];
            sXi[it * 256 + t] = ai4[it * 256 + t];
        }
    }
    __syncthreads();

    const int el = t & 31;
    const int kg = t >> 5;                 // 0..7, owns k = 2kg, 2kg+1
    const int e  = slice * 32 + el;

    float pr0 = 0.f, pr1 = 0.f, pi0 = 0.f, pi1 = 0.f;
#pragma unroll 8
    for (int ds = 0; ds < 64; ++ds) {
        const float4 w  = sW[el * 64 + (ds ^ (el & 7))];
        const float4 a0 = sXr[(kg * 2) * 64 + ds];       // bcast (half-wave)
        const float4 a1 = sXr[(kg * 2 + 1) * 64 + ds];
        const float4 c0 = sXi[(kg * 2) * 64 + ds];
        const float4 c1 = sXi[(kg * 2 + 1) * 64 + ds];
        pr0 += w.x * a0.x + w.y * a0.y + w.z * a0.z + w.w * a0.w;
        pr1 += w.x * a1.x + w.y * a1.y + w.z * a1.z + w.w * a1.w;
        pi0 += w.x * c0.x + w.y * c0.y + w.z * c0.z + w.w * c0.w;
        pi1 += w.x * c1.x + w.y * c1.y + w.z * c1.z + w.w * c1.w;
    }

    sNrm[kg * 32 + el] = pr0 * pr0 + pi0 * pi0 + pr1 * pr1 + pi1 * pi1;
    __syncthreads();
    if (t < 32) {
        float nrm = 0.f;
#pragma unroll
        for (int w = 0; w < 8; ++w) nrm += sNrm[w * 32 + t];
        sSg[t] = 1.f / (1.f + expf(-sqrtf(nrm)));
    }
    __syncthreads();
    const float sg = sSg[el];

    float* base0 = o0 + (size_t)g * KD + (kg * 2) * D + e;
    if (LAYER == 1) {
        float* base1 = o1 + (size_t)g * KD + (kg * 2) * D + e;
        base0[0] = pr0 * sg; base0[D] = pr1 * sg;
        base1[0] = pi0 * sg; base1[D] = pi1 * sg;
    } else {
        const float f0 = fs[e * 2], f1 = fs[e * 2 + 1];
        base0[0] = (pr0 * f0 + pi0 * f1) * sg;
        base0[D] = (pr1 * f0 + pi1 * f1) * sg;
    }
}

// ---------------------------------------------------------------------------
// Stage 3: out[n,d] = x[n,d] + sum_k V[n,k] * z[g,k,d]
// grid = G*16 x 256T; wave nq owns rows nq*32.. (disjoint); z slice in 16
// float4 regs; V via LDS broadcast; NT stores. No min-wave bound (avoid
// VGPR cap -> spills with 64-reg zr + unroll-8 loads).
// ---------------------------------------------------------------------------
__global__ __launch_bounds__(256) void k_back(const float* __restrict__ x,
                                              const float* __restrict__ eig,
                                              const float* __restrict__ z,
                                              float* __restrict__ out) {
    __shared__ float sV[BROWS * K];      // 8 KB
    const int b  = blockIdx.x;
    const int g  = b >> 4, c = b & 15;
    const int n0 = g * NG + c * BROWS;
    const int t  = threadIdx.x;
    const int d4 = t & 63;
    const int nq = t >> 6;
    {
        const float4* e4 = (const float4*)(eig + (size_t)n0 * K);
        float4* s4 = (float4*)sV;
        s4[t]       = e4[t];
        s4[t + 256] = e4[t + 256];
    }
    float4 zr[K];
    const float4* z4 = (const float4*)z + (size_t)g * (KD / 4);
#pragma unroll
    for (int k = 0; k < K; ++k) zr[k] = z4[k * 64 + d4];
    __syncthreads();

    const float4* x4 = (const float4*)x + ((size_t)n0 + nq * 32) * 64;
    v4f* o4 = (v4f*)out + ((size_t)n0 + nq * 32) * 64;
    const float* vbase = sV + nq * 32 * K;
#pragma unroll 8
    for (int n = 0; n < 32; ++n) {
        float4 o = x4[n * 64 + d4];
#pragma unroll
        for (int kq = 0; kq < 4; ++kq) {
            const float4 v = *(const float4*)&vbase[n * K + kq * 4];  // bcast
            o.x += v.x * zr[kq*4+0].x + v.y * zr[kq*4+1].x + v.z * zr[kq*4+2].x + v.w * zr[kq*4+3].x;
            o.y += v.x * zr[kq*4+0].y + v.y * zr[kq*4+1].y + v.z * zr[kq*4+2].y + v.w * zr[kq*4+3].y;
            o.z += v.x * zr[kq*4+0].z + v.y * zr[kq*4+1].z + v.z * zr[kq*4+2].z + v.w * zr[kq*4+3].z;
            o.w += v.x * zr[kq*4+0].w + v.y * zr[kq*4+1].w + v.z * zr[kq*4+2].w + v.w * zr[kq*4+3].w;
        }
        v4f ov; ov.x = o.x; ov.y = o.y; ov.z = o.z; ov.w = o.w;
        __builtin_nontemporal_store(ov, &o4[n * 64 + d4]);
    }
}

// ---------------------------------------------------------------------------
extern "C" void kernel_launch(void* const* d_in, const int* in_sizes, int n_in,
                              void* d_out, int out_size, void* d_ws, size_t ws_size,
                              hipStream_t stream) {
    const float* x    = (const float*)d_in[0];
    const float* eig  = (const float*)d_in[1];
    const float* sr   = (const float*)d_in[2];
    const float* si   = (const float*)d_in[3];
    const float* filt = (const float*)d_in[4];
    const float* W1   = (const float*)d_in[5];
    const float* W2   = (const float*)d_in[6];
    const float* fs   = (const float*)d_in[7];
    float* out = (float*)d_out;

    // Scratch carved from d_out (128MiB; fully overwritten by k_back last):
    //   WP: 512 x KD = 8.4MB of chunk partials, then Xr/Xi/y1r/y1i (1MB each).
    float* WP  = out;
    float* Xr  = out + WPF;
    float* Xi  = Xr + (size_t)G * KD;
    float* y1r = Xi + (size_t)G * KD;
    float* y1i = y1r + (size_t)G * KD;
    // z is read by k_back while it writes d_out -> lives in ws.
    float* z   = (float*)d_ws;

    k_project<<<G * NCHUNK, 256, 0, stream>>>(x, eig, WP);
    k_reduce<<<G * 4, 256, 0, stream>>>(WP, filt, sr, si, Xr, Xi);
    k_mlp<1><<<G * 8, 256, 0, stream>>>(Xr, Xi, W1, nullptr, y1r, y1i);
    k_mlp<2><<<G * 8, 256, 0, stream>>>(y1r, y1i, W2, fs, z, nullptr);
    k_back<<<G * BCHUNK, 256, 0, stream>>>(x, eig, z, out);
}